// Round 6
// baseline (181.319 us; speedup 1.0000x reference)
//
#include <hip/hip_runtime.h>
#include <hip/hip_bf16.h>

// Problem dims (fixed): B=2, M=L=2048, H=1024, K_HEADS=16, D=64
// All inputs/output are FLOAT32; compute in bf16 MFMA with f32 accumulation.
// Algebra: softmax branch is dead; out = Q (K^T V) blockdiag Wo^T.
// Gram path: T_h = K_h^T V_h = Wk_h (hc^T hc) Wv_h^T:
//   G_b  = hcT_b @ hcT_b^T   (symmetric: 136 upper-tri 64^2 tiles + fill)
//   q_b  = h_b @ Wq^T        (fused with G in one dispatch)
//   T_h  = Wk_h G_b Wv_h^T   (fused, split over k'-tiles, atomics into Sbuf)
//   W2[n][h*64+dp] = sum_d Wo[n][h*64+d] T[h][dp][d]
//   out_b = q_b @ W2_b^T
// Round 15: m97-structure 128x128 GEMM body (4 waves x 4x4 16x16x32-MFMA
// fragments, 32 MFMA/wave per BK=64 step) for q and final — the per-kernel
// GEMM engine was the bottleneck (~200 TF), not the decomposition.
#define BB 2
#define MM 2048
#define HH 1024
#define KH 16

typedef short s16x8 __attribute__((ext_vector_type(8)));
typedef float f32x4 __attribute__((ext_vector_type(4)));
typedef float f32x16 __attribute__((ext_vector_type(16)));

#define GLOBAL_AS __attribute__((address_space(1)))
#define LDS_AS    __attribute__((address_space(3)))

__device__ __forceinline__ void async_copy16(const void* g, void* l) {
    __builtin_amdgcn_global_load_lds((const GLOBAL_AS void*)g, (LDS_AS void*)l, 16, 0, 0);
}

struct __align__(8) bf16x4_t { __hip_bfloat16 x, y, z, w; };

// ---------------------------------------------------------------------------
// fused prep: fp32->bf16 converts + hc transpose + Sbuf zero: grid (4096, 6)
// seg 0: convert h; seg 1: bx<1024 transpose-convert hc -> hcT, 1024<=bx<1152
//        zero Sbuf; seg 2/3/4: convert Wk/Wv/Wo; seg 5: convert Wq (plain)
// ---------------------------------------------------------------------------
__global__ __launch_bounds__(256) void cvt_all(
    const float* __restrict__ h_f, const float* __restrict__ hc_f,
    const float* __restrict__ Wk_f, const float* __restrict__ Wv_f,
    const float* __restrict__ Wo_f, const float* __restrict__ Wq_f,
    __hip_bfloat16* __restrict__ hb, __hip_bfloat16* __restrict__ hcT,
    __hip_bfloat16* __restrict__ wkb, __hip_bfloat16* __restrict__ wvb,
    __hip_bfloat16* __restrict__ wob, __hip_bfloat16* __restrict__ wqb,
    float* __restrict__ Sz)
{
    __shared__ float Tl[64][65];
    const int seg = blockIdx.y;
    const int t = threadIdx.x;
    const int bx = blockIdx.x;

    if (seg == 1) {
        if (bx < BB * 512) {               // hc -> hcT (per-b [1024][2048])
            const int b = bx >> 9;
            const int tile = bx & 511;
            const int m0 = (tile >> 4) * 64;   // 32 m-tiles
            const int k0 = (tile & 15) * 64;   // 16 k-tiles
            const int r = t >> 6;
            const int c = t & 63;
            const float* src = hc_f + (size_t)b * MM * HH;
#pragma unroll
            for (int i = 0; i < 64; i += 4)
                Tl[r + i][c] = src[(size_t)(m0 + r + i) * HH + k0 + c];
            __syncthreads();
            __hip_bfloat16* dst = hcT + (size_t)b * HH * MM;
            const int ml = (t & 15) * 4;
#pragma unroll
            for (int ii = 0; ii < 4; ++ii) {
                const int kl = (t >> 4) + 16 * ii;
                bf16x4_t o;
                o.x = __float2bfloat16(Tl[ml + 0][kl]);
                o.y = __float2bfloat16(Tl[ml + 1][kl]);
                o.z = __float2bfloat16(Tl[ml + 2][kl]);
                o.w = __float2bfloat16(Tl[ml + 3][kl]);
                *(bf16x4_t*)(dst + (size_t)(k0 + kl) * MM + m0 + ml) = o;
            }
        } else if (bx < BB * 512 + 128) {  // zero Sbuf: 131072 floats
            const int i = ((bx - BB * 512) * 256 + t) * 4;
            float4 z = {0.f, 0.f, 0.f, 0.f};
            *(float4*)(Sz + i) = z;
        }
        return;
    }
    const float* src;
    __hip_bfloat16* dst;
    int n;
    switch (seg) {
        case 0: src = h_f;  dst = hb;  n = BB * MM * HH; break;
        case 2: src = Wk_f; dst = wkb; n = HH * HH; break;
        case 3: src = Wv_f; dst = wvb; n = HH * HH; break;
        case 4: src = Wo_f; dst = wob; n = HH * HH; break;
        default: src = Wq_f; dst = wqb; n = HH * HH; break;
    }
    const int i = (bx * 256 + t) * 4;
    if (i + 3 < n) {
        const float4 v = *(const float4*)(src + i);
        bf16x4_t o;
        o.x = __float2bfloat16(v.x);
        o.y = __float2bfloat16(v.y);
        o.z = __float2bfloat16(v.z);
        o.w = __float2bfloat16(v.w);
        *(bf16x4_t*)(dst + i) = o;
    }
}

// ---------------------------------------------------------------------------
// store helpers
// ---------------------------------------------------------------------------
__device__ __forceinline__ void store_c(__hip_bfloat16* C, size_t idx, float v) {
    C[idx] = __float2bfloat16(v);
}
__device__ __forceinline__ void store_c(float* C, size_t idx, float v) { C[idx] = v; }

// ---------------------------------------------------------------------------
// m97-structure 128x128 NT GEMM body: 4 waves, each owns a 64x64 output as
// 4x4 fragments of 16x16x32 MFMA. Per BK=64 step per wave: 8 async stage
// loads, 16 ds_read_b128, 32 MFMA. LDS: A 16 KB + B 16 KB, XOR-swizzled
// 64-col rows (element (r,k) at byte r*128 + ((k/8)^(r&7))*16 + (k%8)*2).
// A/B pre-offset to tile origin. acc indexed statically (full unroll).
// ---------------------------------------------------------------------------
__device__ __forceinline__ void nt128_body(
    const __hip_bfloat16* __restrict__ A, const __hip_bfloat16* __restrict__ B,
    int kd, size_t lda, size_t ldb,
    __hip_bfloat16* As, __hip_bfloat16* Bs, f32x4 acc[4][4])
{
    const int t    = threadIdx.x;
    const int lane = t & 63;
    const int wave = t >> 6;
    const int srow = lane >> 3;
    const int sw   = ((lane & 7) ^ srow) * 8;
    const int wr   = (wave >> 1) * 64;   // m-quadrant
    const int wc   = (wave & 1) * 64;    // n-quadrant
    const int fm16 = lane & 15;
    const int kh   = lane >> 4;          // 0..3

    for (int k0 = 0; k0 < kd; k0 += 64) {
        __syncthreads();
#pragma unroll
        for (int i = 0; i < 4; ++i) {
            const int c = wave * 4 + i;          // 16 wave-loads cover 128 rows
            async_copy16(A + (size_t)(c * 8 + srow) * lda + k0 + sw, As + c * 512);
            async_copy16(B + (size_t)(c * 8 + srow) * ldb + k0 + sw, Bs + c * 512);
        }
        __syncthreads();
#pragma unroll
        for (int ks = 0; ks < 2; ++ks) {         // two 32-wide k-slices
            s16x8 af[4], bf[4];
#pragma unroll
            for (int mi = 0; mi < 4; ++mi) {
                const int row = wr + mi * 16 + fm16;
                af[mi] = *(const s16x8*)(As + row * 64 + (((ks * 4 + kh) ^ (row & 7)) * 8));
            }
#pragma unroll
            for (int nj = 0; nj < 4; ++nj) {
                const int row = wc + nj * 16 + fm16;
                bf[nj] = *(const s16x8*)(Bs + row * 64 + (((ks * 4 + kh) ^ (row & 7)) * 8));
            }
#pragma unroll
            for (int mi = 0; mi < 4; ++mi)
#pragma unroll
                for (int nj = 0; nj < 4; ++nj)
                    acc[mi][nj] = __builtin_amdgcn_mfma_f32_16x16x32_bf16(
                        af[mi], bf[nj], acc[mi][nj], 0, 0, 0);
        }
    }
}

// store the 128x128 tile (C pre-offset to tile origin)
template <typename OutT>
__device__ __forceinline__ void store_tile128(OutT* C, int ldc, f32x4 acc[4][4]) {
    const int lane = threadIdx.x & 63;
    const int wave = threadIdx.x >> 6;
    const int wr = (wave >> 1) * 64;
    const int wc = (wave & 1) * 64;
    const int er = (lane >> 4) * 4;
    const int ec = lane & 15;
#pragma unroll
    for (int mi = 0; mi < 4; ++mi)
#pragma unroll
        for (int nj = 0; nj < 4; ++nj)
#pragma unroll
            for (int rr = 0; rr < 4; ++rr)
                store_c(C, (size_t)(wr + mi * 16 + er + rr) * ldc + wc + nj * 16 + ec,
                        acc[mi][nj][rr]);
}

// ---------------------------------------------------------------------------
// 64x64-tile BK=64 NT GEMM body, double-buffered (verified rounds 14) —
// used for the G tiles and vt stage 1.
// ---------------------------------------------------------------------------
__device__ __forceinline__ f32x16 nt64_db_acc(
    const __hip_bfloat16* __restrict__ A, const __hip_bfloat16* __restrict__ B,
    int kd, size_t ld, __hip_bfloat16* As, __hip_bfloat16* Bs)
{
    const int t    = threadIdx.x;
    const int lane = t & 63;
    const int wave = t >> 6;
    const int srow = lane >> 3;
    const int sw   = ((lane & 7) ^ srow) * 8;
    const int wm   = (wave >> 1) * 32;
    const int wn   = (wave & 1) * 32;
    const int fm   = lane & 31;
    const int fm7  = fm & 7;
    const int ghi  = lane >> 5;

#pragma unroll
    for (int i = 0; i < 2; ++i) {
        const int c = wave * 2 + i;
        async_copy16(A + (size_t)(c * 8 + srow) * ld + sw, As + c * 512);
        async_copy16(B + (size_t)(c * 8 + srow) * ld + sw, Bs + c * 512);
    }
    __syncthreads();

    f32x16 acc = {};
    int cur = 0;
    for (int k0 = 0; k0 < kd; k0 += 64) {
        const int nxt = cur ^ 1;
        if (k0 + 64 < kd) {
#pragma unroll
            for (int i = 0; i < 2; ++i) {
                const int c = wave * 2 + i;
                async_copy16(A + (size_t)(c * 8 + srow) * ld + (k0 + 64) + sw,
                             As + nxt * 4096 + c * 512);
                async_copy16(B + (size_t)(c * 8 + srow) * ld + (k0 + 64) + sw,
                             Bs + nxt * 4096 + c * 512);
            }
        }
#pragma unroll
        for (int ks = 0; ks < 64; ks += 16) {
            const int pos = ((((ks >> 3) + ghi) ^ fm7) * 8);
            const s16x8 af = *(const s16x8*)(As + cur * 4096 + (wm + fm) * 64 + pos);
            const s16x8 bf = *(const s16x8*)(Bs + cur * 4096 + (wn + fm) * 64 + pos);
            acc = __builtin_amdgcn_mfma_f32_32x32x16_bf16(af, bf, acc, 0, 0, 0);
        }
        __syncthreads();
        cur = nxt;
    }
    return acc;
}

// direct store of the 64x64 tile (C pre-offset to tile origin)
template <typename OutT>
__device__ __forceinline__ void store_tile64(OutT* C, int ldc, const f32x16& acc) {
    const int lane = threadIdx.x & 63;
    const int wave = threadIdx.x >> 6;
    const int wm = (wave >> 1) * 32;
    const int wn = (wave & 1) * 32;
    const int col = wn + (lane & 31);
    const int rb  = 4 * (lane >> 5);
#pragma unroll
    for (int r = 0; r < 16; ++r) {
        const int row = wm + (r & 3) + 8 * (r >> 2) + rb;
        store_c(C, (size_t)row * ldc + col, acc[r]);
    }
}

// ---------------------------------------------------------------------------
// MEGA dispatch: q-projection (128^2 m97 tiles) + Gram (64^2 sym tiles).
// grid (264, 1, BB):
//   bx <  128: q_b 128x128 tile (q = h @ Wq^T, NT, K=1024)
//   bx >= 128: G_b upper-tri 64x64 tile (G = hcT @ hcT^T, K=2048) + fill
// ---------------------------------------------------------------------------
__global__ __launch_bounds__(256) void mega_gq(
    const __hip_bfloat16* __restrict__ hb, const __hip_bfloat16* __restrict__ wqb,
    const __hip_bfloat16* __restrict__ hcT,
    __hip_bfloat16* __restrict__ qb, __hip_bfloat16* __restrict__ G)
{
    __shared__ __align__(16) char smem[32768];
    __hip_bfloat16* As = (__hip_bfloat16*)smem;
    __hip_bfloat16* Bs = (__hip_bfloat16*)(smem + 16384);
    __hip_bfloat16* Ts = (__hip_bfloat16*)smem;             // 64x72 bounce

    const int b = blockIdx.z;
    const int bx = blockIdx.x;

    if (bx < 128) {                        // q tile (128x128)
        const int m0 = (bx >> 3) * 128, n0 = (bx & 7) * 128;
        f32x4 acc[4][4] = {};
        nt128_body(hb + (size_t)b * MM * HH + (size_t)m0 * HH,
                   wqb + (size_t)n0 * HH, HH, HH, HH, As, Bs, acc);
        store_tile128(qb + (size_t)b * MM * HH + (size_t)m0 * HH + n0, HH, acc);
        return;
    }

    // G upper-tri 64x64 tile: decode (i<=j) from bx-128 in [0,136)
    int i = 0, rem = bx - 128;
    while (rem >= 16 - i) { rem -= 16 - i; ++i; }
    const int j = i + rem;
    const int m0 = i * 64, n0 = j * 64;

    const __hip_bfloat16* Ab = hcT + (size_t)b * HH * MM;
    f32x16 acc = nt64_db_acc(Ab + (size_t)m0 * MM, Ab + (size_t)n0 * MM, MM, MM, As, Bs);

    __hip_bfloat16* Gb = G + (size_t)b * HH * HH;
    store_tile64(Gb + (size_t)m0 * HH + n0, HH, acc);

    if (i == j) return;

    // transpose fill of tile (j,i) via LDS bounce
    __syncthreads();
    {
        const int lane = threadIdx.x & 63;
        const int wave = threadIdx.x >> 6;
        const int wm = (wave >> 1) * 32;
        const int wn = (wave & 1) * 32;
        const int col = wn + (lane & 31);
        const int rb  = 4 * (lane >> 5);
#pragma unroll
        for (int r = 0; r < 16; ++r) {
            const int row = wm + (r & 3) + 8 * (r >> 2) + rb;
            Ts[row * 72 + col] = __float2bfloat16(acc[r]);
        }
    }
    __syncthreads();
    {
        const int t = threadIdx.x;
        const int rp = t >> 2;
        const int c0 = (t & 3) * 16;
        __hip_bfloat16* dst = Gb + (size_t)(n0 + rp) * HH + m0 + c0;
#pragma unroll
        for (int kk = 0; kk < 4; ++kk) {
            bf16x4_t o;
            o.x = Ts[(c0 + 4 * kk + 0) * 72 + rp];
            o.y = Ts[(c0 + 4 * kk + 1) * 72 + rp];
            o.z = Ts[(c0 + 4 * kk + 2) * 72 + rp];
            o.w = Ts[(c0 + 4 * kk + 3) * 72 + rp];
            *(bf16x4_t*)(dst + 4 * kk) = o;
        }
    }
}

// ---------------------------------------------------------------------------
// FUSED T_h = Wk_h G_b Wv_h^T, split over k'-tiles: grid (16, KH, BB) = 512
// (verified rounds 8/11-14)
// ---------------------------------------------------------------------------
#define LPP 72

__global__ __launch_bounds__(256) void gemm_vt(
    const __hip_bfloat16* __restrict__ wkb, const __hip_bfloat16* __restrict__ wvb,
    const __hip_bfloat16* __restrict__ G, float* __restrict__ S)
{
    __shared__ __align__(16) char smem[32768];
    __hip_bfloat16* As = (__hip_bfloat16*)smem;
    __hip_bfloat16* Bs = (__hip_bfloat16*)(smem + 16384);
    __hip_bfloat16* Pl = (__hip_bfloat16*)smem;
    __hip_bfloat16* Wl = (__hip_bfloat16*)(smem + 64 * LPP * 2);

    const int t    = threadIdx.x;
    const int lane = t & 63;
    const int wave = t >> 6;
    const int kt   = blockIdx.x;
    const int head = blockIdx.y;
    const int b    = blockIdx.z;

    const __hip_bfloat16* Arow = G + (size_t)b * HH * HH + (size_t)kt * 64 * HH;
    const __hip_bfloat16* Brow = wkb + (size_t)head * 64 * HH;

    f32x16 acc = nt64_db_acc(Arow, Brow, HH, HH, As, Bs);
    __syncthreads();

    {
        const int wm = (wave >> 1) * 32;
        const int wn = (wave & 1) * 32;
        const int col_i = wn + (lane & 31);
        const int ghi4  = 4 * (lane >> 5);
#pragma unroll
        for (int g = 0; g < 4; ++g) {
            const int ccb = wm + 8 * g + ghi4;
            bf16x4_t o;
            o.x = __float2bfloat16(acc[4 * g + 0]);
            o.y = __float2bfloat16(acc[4 * g + 1]);
            o.z = __float2bfloat16(acc[4 * g + 2]);
            o.w = __float2bfloat16(acc[4 * g + 3]);
            *(bf16x4_t*)(Pl + col_i * LPP + ccb) = o;
        }
    }
    {
        const int srow = lane >> 3;
        const int sw   = ((lane & 7) ^ srow) * 8;
#pragma unroll
        for (int i = 0; i < 2; ++i) {
            const int c = wave * 2 + i;
            async_copy16(wvb + (size_t)(head * 64 + c * 8 + srow) * HH + kt * 64 + sw,
                         Wl + c * 512);
        }
    }
    __syncthreads();

    const int fr  = lane & 15;
    const int fq  = (lane >> 4) * 8;
    const int wm2 = wave * 16;

    f32x4 acc2[4] = {};
#pragma unroll
    for (int kk = 0; kk < 64; kk += 32) {
        const s16x8 af = *(const s16x8*)(Pl + (wm2 + fr) * LPP + kk + fq);
#pragma unroll
        for (int nj = 0; nj < 4; ++nj) {
            const int row = nj * 16 + fr;
            const s16x8 bfv = *(const s16x8*)(
                Wl + row * 64 + ((((kk + fq) >> 3) ^ (row & 7)) << 3));
            acc2[nj] = __builtin_amdgcn_mfma_f32_16x16x32_bf16(af, bfv, acc2[nj], 0, 0, 0);
        }
    }

    float* Sg = S + ((size_t)b * KH + head) * 4096;
    const int er = (lane >> 4) * 4;
    const int ec = lane & 15;
#pragma unroll
    for (int nj = 0; nj < 4; ++nj)
#pragma unroll
        for (int rr = 0; rr < 4; ++rr)
            atomicAdd(&Sg[(wm2 + er + rr) * 64 + nj * 16 + ec], acc2[nj][rr]);
}

// ---------------------------------------------------------------------------
// out_b = q_b @ W2_b^T, fp32 out, 128x128 m97 tiles: grid (128, 1, BB)
// ---------------------------------------------------------------------------
__global__ __launch_bounds__(256) void gemm_final2(
    const __hip_bfloat16* __restrict__ qb, const __hip_bfloat16* __restrict__ W2,
    float* __restrict__ outg)
{
    __shared__ __align__(16) char smem[32768];
    __hip_bfloat16* As = (__hip_bfloat16*)smem;
    __hip_bfloat16* Bs = (__hip_bfloat16*)(smem + 16384);
    const int b = blockIdx.z;
    const int m0 = (blockIdx.x >> 3) * 128, n0 = (blockIdx.x & 7) * 128;
    f32x4 acc[4][4] = {};
    nt128_body(qb + (size_t)b * MM * HH + (size_t)m0 * HH,
               W2 + (size_t)b * HH * HH + (size_t)n0 * HH, HH, HH, HH, As, Bs, acc);
    store_tile128(outg + (size_t)b * MM * HH + (size_t)m0 * HH + n0, HH, acc);
}

// ---------------------------------------------------------------------------
// W2[b][n][h*64+dp] = sum_d Wo[n][h*64+d] * T[b,h,dp,d]   (bf16 out)
// grid (8, KH, BB), block 256  (verified rounds 2-14)
// ---------------------------------------------------------------------------
__global__ __launch_bounds__(256) void w2_fold(
    const __hip_bfloat16* __restrict__ Wo,
    const float* __restrict__ S,
    __hip_bfloat16* __restrict__ W2)
{
    __shared__ float Sl[64 * 68];
    __shared__ float Wl[128 * 68];
    const int t = threadIdx.x, head = blockIdx.y, b = blockIdx.z;
    const int n0 = blockIdx.x * 128;

    const float* Sg = S + ((size_t)b * KH + head) * 4096;
    for (int idx = t; idx < 4096; idx += 256) {
        const int dp = idx >> 6, d = idx & 63;
        Sl[d * 68 + dp] = Sg[idx];
    }
    for (int idx = t; idx < 1024; idx += 256) {
        const int r = idx >> 3, c8 = (idx & 7) * 8;
        s16x8 wv = *(const s16x8*)(Wo + (size_t)(n0 + r) * HH + head * 64 + c8);
#pragma unroll
        for (int j = 0; j < 8; ++j) {
            __hip_bfloat16 wb = *(((const __hip_bfloat16*)&wv) + j);
            Wl[r * 68 + c8 + j] = __bfloat162float(wb);
        }
    }
    __syncthreads();

    const int dpb = (t & 15) * 4;
    const int ng  = t >> 4;
    float acc[8][4] = {};
    for (int d0 = 0; d0 < 64; d0 += 4) {
        f32x4 sv[4];
#pragma unroll
        for (int r = 0; r < 4; ++r)
            sv[r] = *(const f32x4*)(Sl + (d0 + r) * 68 + dpb);
#pragma unroll
        for (int i = 0; i < 8; ++i) {
            const f32x4 wv = *(const f32x4*)(Wl + (ng + 16 * i) * 68 + d0);
#pragma unroll
            for (int r = 0; r < 4; ++r)
#pragma unroll
                for (int j = 0; j < 4; ++j)
                    acc[i][j] += wv[r] * sv[r][j];
        }
    }

#pragma unroll
    for (int i = 0; i < 8; ++i) {
        bf16x4_t o;
        o.x = __float2bfloat16(acc[i][0]);
        o.y = __float2bfloat16(acc[i][1]);
        o.z = __float2bfloat16(acc[i][2]);
        o.w = __float2bfloat16(acc[i][3]);
        *(bf16x4_t*)(W2 + (size_t)b * HH * HH + (size_t)(n0 + ng + 16 * i) * HH
                     + head * 64 + dpb) = o;
    }
}

// ---------------------------------------------------------------------------
extern "C" void kernel_launch(void* const* d_in, const int* in_sizes, int n_in,
                              void* d_out, int out_size, void* d_ws, size_t ws_size,
                              hipStream_t stream) {
    const float* h_f  = (const float*)d_in[0];
    const float* hc_f = (const float*)d_in[1];
    // d_in[2] = key_pe: DEAD (softmax result unused by reference output)
    const float* Wq_f = (const float*)d_in[3];
    const float* Wk_f = (const float*)d_in[4];
    const float* Wv_f = (const float*)d_in[5];
    const float* Wo_f = (const float*)d_in[6];
    float* out = (float*)d_out;

    const size_t act_b = (size_t)BB * MM * HH * 2;  // 8 MB
    const size_t w_b   = (size_t)HH * HH * 2;       // 2 MB
    char* ws = (char*)d_ws;
    __hip_bfloat16* hb   = (__hip_bfloat16*)(ws);                       // 8 MB
    __hip_bfloat16* hcT  = (__hip_bfloat16*)(ws + act_b);               // 8 MB ([b][k][m])
    __hip_bfloat16* wkb  = (__hip_bfloat16*)(ws + 2 * act_b);           // 2 MB
    __hip_bfloat16* wvb  = (__hip_bfloat16*)(ws + 2 * act_b + w_b);     // 2 MB
    __hip_bfloat16* wob  = (__hip_bfloat16*)(ws + 2 * act_b + 2 * w_b); // 2 MB
    __hip_bfloat16* wqb  = (__hip_bfloat16*)(ws + 2 * act_b + 3 * w_b); // 2 MB
    __hip_bfloat16* qb   = (__hip_bfloat16*)(ws + 2 * act_b + 4 * w_b); // 8 MB
    __hip_bfloat16* Gb   = (__hip_bfloat16*)(ws + 3 * act_b + 4 * w_b); // 4 MB
    float*          Sbuf = (float*)(ws + 3 * act_b + 6 * w_b);          // 512 KB
    __hip_bfloat16* W2   = (__hip_bfloat16*)(ws + 3 * act_b + 6 * w_b + (size_t)512 * 1024);  // 4 MB

    const dim3 blk(256);

    // 0: all prep in one dispatch (converts + hc transpose + Sbuf zero)
    cvt_all<<<dim3(4096, 6), blk, 0, stream>>>(h_f, hc_f, Wk_f, Wv_f, Wo_f, Wq_f,
                                               hb, hcT, wkb, wvb, wob, wqb, Sbuf);

    // 1: MEGA: q = h Wq^T (128^2 tiles) + G = hcT hcT^T (64^2 sym tiles)
    mega_gq<<<dim3(264, 1, BB), blk, 0, stream>>>(hb, wqb, hcT, qb, Gb);

    // 2: T_h = Wk_h G_b Wv_h^T fused (atomic partials into zeroed Sbuf)
    gemm_vt<<<dim3(16, KH, BB), blk, 0, stream>>>(wkb, wvb, Gb, Sbuf);

    // 3: W2 = blockdiag(T) folded into Wo
    w2_fold<<<dim3(8, KH, BB), blk, 0, stream>>>(wob, Sbuf, W2);

    // 4: out = q @ W2^T (fp32 out), 128^2 tiles
    gemm_final2<<<dim3(128, 1, BB), blk, 0, stream>>>(qb, W2, out);
}

// Round 7
// 163.583 us; speedup vs baseline: 1.1084x; 1.1084x over previous
//
#include <hip/hip_runtime.h>
#include <hip/hip_bf16.h>

// Problem dims (fixed): B=2, M=L=2048, H=1024, K_HEADS=16, D=64
// All inputs/output are FLOAT32; compute in bf16 MFMA with f32 accumulation.
// Algebra: softmax branch is dead; out = Q (K^T V) blockdiag Wo^T, folded as
//   T_h = K_h^T V_h (per head, 64x64)          [fused into the K/V projection]
//   W2[n][h*64+dp] = sum_d Wo[n][h*64+d] T[h][dp][d]
//   q_b  = h_b @ Wq^T                          [re-assoc: out = (h Wq^T) W2^T]
//   out_b = q_b @ W2_b^T
// Round 16: measured-best R9 structure + re-association. gemm_f deleted;
// q-projection fused into the kvt dispatch (independent chains). 4 dispatches.
// All GEMM bodies verbatim from the verified R9 kernel.
#define BB 2
#define MM 2048
#define HH 1024
#define KH 16

typedef short s16x8 __attribute__((ext_vector_type(8)));
typedef float f32x4 __attribute__((ext_vector_type(4)));
typedef float f32x16 __attribute__((ext_vector_type(16)));

#define GLOBAL_AS __attribute__((address_space(1)))
#define LDS_AS    __attribute__((address_space(3)))

__device__ __forceinline__ void async_copy16(const void* g, void* l) {
    __builtin_amdgcn_global_load_lds((const GLOBAL_AS void*)g, (LDS_AS void*)l, 16, 0, 0);
}

struct __align__(8) bf16x4_t { __hip_bfloat16 x, y, z, w; };

// ---------------------------------------------------------------------------
// fused prep: fp32->bf16 converts + Sbuf zero: grid (4096, 6)
// segs 0-4: convert h, h_cache, Wk, Wv, Wo
// seg 5: bx<128 -> zero Sbuf; 128<=bx<1152 -> convert Wq (plain, row-major)
// ---------------------------------------------------------------------------
__global__ __launch_bounds__(256) void cvt_all(
    const float* __restrict__ s0, const float* __restrict__ s1,
    const float* __restrict__ s2, const float* __restrict__ s3,
    const float* __restrict__ s4, const float* __restrict__ Wq,
    __hip_bfloat16* __restrict__ d0, __hip_bfloat16* __restrict__ d1,
    __hip_bfloat16* __restrict__ d2, __hip_bfloat16* __restrict__ d3,
    __hip_bfloat16* __restrict__ d4, __hip_bfloat16* __restrict__ wqb,
    float* __restrict__ Sz)
{
    const int seg = blockIdx.y;
    const int t = threadIdx.x;
    if (seg == 5) {
        const int bx = blockIdx.x;
        if (bx < 128) {                        // zero Sbuf: 131072 floats
            const int i = (bx * 256 + t) * 4;
            float4 z = {0.f, 0.f, 0.f, 0.f};
            *(float4*)(Sz + i) = z;
        } else if (bx < 1152) {                // convert Wq (1024x1024)
            const int i = ((bx - 128) * 256 + t) * 4;
            const float4 v = *(const float4*)(Wq + i);
            bf16x4_t o;
            o.x = __float2bfloat16(v.x);
            o.y = __float2bfloat16(v.y);
            o.z = __float2bfloat16(v.z);
            o.w = __float2bfloat16(v.w);
            *(bf16x4_t*)(wqb + i) = o;
        }
        return;
    }
    const float* src;
    __hip_bfloat16* dst;
    int n;
    switch (seg) {
        case 0: src = s0; dst = d0; n = BB * MM * HH; break;
        case 1: src = s1; dst = d1; n = BB * MM * HH; break;
        case 2: src = s2; dst = d2; n = HH * HH; break;
        case 3: src = s3; dst = d3; n = HH * HH; break;
        default: src = s4; dst = d4; n = HH * HH; break;
    }
    const int i = (blockIdx.x * 256 + t) * 4;
    if (i + 3 < n) {
        const float4 v = *(const float4*)(src + i);
        bf16x4_t o;
        o.x = __float2bfloat16(v.x);
        o.y = __float2bfloat16(v.y);
        o.z = __float2bfloat16(v.z);
        o.w = __float2bfloat16(v.w);
        *(bf16x4_t*)(dst + i) = o;
    }
}

// ---------------------------------------------------------------------------
// store helpers
// ---------------------------------------------------------------------------
__device__ __forceinline__ void store_c(__hip_bfloat16* C, size_t idx, float v) {
    C[idx] = __float2bfloat16(v);
}
__device__ __forceinline__ void store_c(float* C, size_t idx, float v) { C[idx] = v; }

// ---------------------------------------------------------------------------
// 64x128-tile BK=64 NT GEMM body (verified rounds 7-9)
// ---------------------------------------------------------------------------
template <typename OutT>
__device__ __forceinline__ void gemm_nt_body64_m64(
    const __hip_bfloat16* __restrict__ A,
    const __hip_bfloat16* __restrict__ Bm,
    OutT* __restrict__ C,
    __hip_bfloat16* As, __hip_bfloat16* Bs,
    int m0, int n0)
{
    const int t    = threadIdx.x;
    const int lane = t & 63;
    const int wave = t >> 6;

    const int srow = lane >> 3;
    const int sw   = ((lane & 7) ^ srow) * 8;

    const int wn  = wave * 32;
    const int fm  = lane & 31;
    const int fm7 = fm & 7;
    const int ghi = lane >> 5;

    f32x16 acc[2] = {};

    for (int k0 = 0; k0 < HH; k0 += 64) {
        __syncthreads();
        {
            const __hip_bfloat16* ag = A + (size_t)(m0 + wave * 16 + srow) * HH + k0 + sw;
            async_copy16(ag,          As + wave * 1024);
            async_copy16(ag + 8 * HH, As + wave * 1024 + 512);
        }
#pragma unroll
        for (int i = 0; i < 2; ++i) {
            const int c = wave * 2 + i;
            const __hip_bfloat16* bg = Bm + (size_t)(n0 + c * 16 + srow) * HH + k0 + sw;
            async_copy16(bg,          Bs + c * 1024);
            async_copy16(bg + 8 * HH, Bs + c * 1024 + 512);
        }
        __syncthreads();

#pragma unroll
        for (int ks = 0; ks < 64; ks += 16) {
            const int pos = ((((ks >> 3) + ghi) ^ fm7) * 8);
            s16x8 af[2], bf;
#pragma unroll
            for (int mi = 0; mi < 2; ++mi)
                af[mi] = *(const s16x8*)(As + (mi * 32 + fm) * 64 + pos);
            bf = *(const s16x8*)(Bs + (wn + fm) * 64 + pos);
#pragma unroll
            for (int mi = 0; mi < 2; ++mi)
                acc[mi] = __builtin_amdgcn_mfma_f32_32x32x16_bf16(
                    af[mi], bf, acc[mi], 0, 0, 0);
        }
    }

    const int ec = lane & 31;
    const int eb = (lane >> 5) * 4;
#pragma unroll
    for (int mi = 0; mi < 2; ++mi)
#pragma unroll
        for (int r = 0; r < 16; ++r) {
            const int m = m0 + mi * 32 + (r & 3) + 8 * (r >> 2) + eb;
            const int n = n0 + wn + ec;
            store_c(C, (size_t)m * HH + n, acc[mi][r]);
        }
}

// ---------------------------------------------------------------------------
// MEGA dispatch: FUSED K/V projection + T = K^T V  (bx < 512, R9-verified)
//                + q = h @ Wq^T tiles              (bx >= 512)
// grid (1024), block 256.
// kvt: Phase 1: K-tile[128x64] = hcb_tile @ Wk_h^T, V-tile likewise; BK=64,
//      XOR-swizzled LDS, 32x32x16 MFMA, K/V stay in registers.
//      Phase 2: acc -> bf16 -> LDS [d][l] (stride 136), T-MFMA + atomics.
// q:   64x128-tile NT body (R9's gemm_f/gemm_final engine), bf16 out.
// ---------------------------------------------------------------------------
#define LP2 136

__global__ __launch_bounds__(256) void mega_kvtq(
    const __hip_bfloat16* __restrict__ hcb,
    const __hip_bfloat16* __restrict__ wk, const __hip_bfloat16* __restrict__ wv,
    const __hip_bfloat16* __restrict__ hb, const __hip_bfloat16* __restrict__ wqb,
    float* __restrict__ S, __hip_bfloat16* __restrict__ qb)
{
    __shared__ __align__(16) char smem[64 * LP2 * 2 * 2];  // 34816 B

    const int t    = threadIdx.x;
    const int lane = t & 63;
    const int wave = t >> 6;
    const int bx   = blockIdx.x;

    if (bx >= 512) {                       // ---- q tile: q = h @ Wq^T ----
        __hip_bfloat16* As = (__hip_bfloat16*)smem;            // 8 KB
        __hip_bfloat16* Bs = (__hip_bfloat16*)(smem + 8192);   // 16 KB
        const int idx = bx - 512;          // 0..511: 64 m-tiles x 8 n-tiles
        const int m0 = (idx >> 3) * 64;    // global row in hb [4096][1024]
        const int n0 = (idx & 7) * 128;
        gemm_nt_body64_m64(hb, wqb, qb, As, Bs, m0, n0);
        return;
    }

    // ---- kvt block (R9-verified verbatim; decode from flattened bx) ----
    __hip_bfloat16* As  = (__hip_bfloat16*)smem;            // 16 KB (128x64)
    __hip_bfloat16* Bsk = (__hip_bfloat16*)(smem + 16384);  //  8 KB (64x64)
    __hip_bfloat16* Bsv = (__hip_bfloat16*)(smem + 24576);  //  8 KB (64x64)
    __hip_bfloat16* Kt  = (__hip_bfloat16*)smem;            // 17408 B (64xLP2)
    __hip_bfloat16* Vt  = (__hip_bfloat16*)(smem + 64 * LP2 * 2);

    const int kx   = bx & 31;
    const int head = bx >> 5;
    const int m0   = kx * 128;
    const int n0   = head * 64;
    const int b    = kx >> 4;

    const int srow = lane >> 3;
    const int sw   = ((lane & 7) ^ srow) * 8;

    const int wm  = (wave >> 1) * 64;
    const int wn  = (wave & 1) * 32;
    const int fm  = lane & 31;
    const int fm7 = fm & 7;
    const int ghi = lane >> 5;

    f32x16 acck[2] = {};
    f32x16 accv[2] = {};

    for (int k0 = 0; k0 < HH; k0 += 64) {
        __syncthreads();
#pragma unroll
        for (int i = 0; i < 4; ++i) {
            const int c = wave * 4 + i;
            async_copy16(hcb + (size_t)(m0 + c * 8 + srow) * HH + k0 + sw,
                         As + c * 512);
        }
#pragma unroll
        for (int i = 0; i < 2; ++i) {
            const int c = wave * 2 + i;
            async_copy16(wk + (size_t)(n0 + c * 8 + srow) * HH + k0 + sw,
                         Bsk + c * 512);
            async_copy16(wv + (size_t)(n0 + c * 8 + srow) * HH + k0 + sw,
                         Bsv + c * 512);
        }
        __syncthreads();

#pragma unroll
        for (int ks = 0; ks < 64; ks += 16) {
            const int pos = ((((ks >> 3) + ghi) ^ fm7) * 8);
            s16x8 af[2];
#pragma unroll
            for (int mi = 0; mi < 2; ++mi)
                af[mi] = *(const s16x8*)(As + (wm + mi * 32 + fm) * 64 + pos);
            const s16x8 bk = *(const s16x8*)(Bsk + (wn + fm) * 64 + pos);
            const s16x8 bv = *(const s16x8*)(Bsv + (wn + fm) * 64 + pos);
#pragma unroll
            for (int mi = 0; mi < 2; ++mi) {
                acck[mi] = __builtin_amdgcn_mfma_f32_32x32x16_bf16(af[mi], bk, acck[mi], 0, 0, 0);
                accv[mi] = __builtin_amdgcn_mfma_f32_32x32x16_bf16(af[mi], bv, accv[mi], 0, 0, 0);
            }
        }
    }

    __syncthreads();

    const int dcol = wn + (lane & 31);
    const int lhi  = 4 * (lane >> 5);
#pragma unroll
    for (int mi = 0; mi < 2; ++mi)
#pragma unroll
        for (int g = 0; g < 4; ++g) {
            const int lb = wm + mi * 32 + 8 * g + lhi;
            bf16x4_t ok, ov;
            ok.x = __float2bfloat16(acck[mi][4 * g + 0]);
            ok.y = __float2bfloat16(acck[mi][4 * g + 1]);
            ok.z = __float2bfloat16(acck[mi][4 * g + 2]);
            ok.w = __float2bfloat16(acck[mi][4 * g + 3]);
            ov.x = __float2bfloat16(accv[mi][4 * g + 0]);
            ov.y = __float2bfloat16(accv[mi][4 * g + 1]);
            ov.z = __float2bfloat16(accv[mi][4 * g + 2]);
            ov.w = __float2bfloat16(accv[mi][4 * g + 3]);
            *(bf16x4_t*)(Kt + dcol * LP2 + lb) = ok;
            *(bf16x4_t*)(Vt + dcol * LP2 + lb) = ov;
        }
    __syncthreads();

    const int fr = lane & 15;
    const int fq = (lane >> 4) * 8;
    const int wm2 = wave * 16;

    f32x4 acc2[4] = {};
#pragma unroll
    for (int kk = 0; kk < 128; kk += 32) {
        const s16x8 af = *(const s16x8*)(Kt + (wm2 + fr) * LP2 + kk + fq);
        s16x8 bf[4];
#pragma unroll
        for (int nj = 0; nj < 4; ++nj)
            bf[nj] = *(const s16x8*)(Vt + (nj * 16 + fr) * LP2 + kk + fq);
#pragma unroll
        for (int nj = 0; nj < 4; ++nj)
            acc2[nj] = __builtin_amdgcn_mfma_f32_16x16x32_bf16(af, bf[nj], acc2[nj], 0, 0, 0);
    }

    float* Sg = S + ((size_t)b * KH + head) * 4096;
    const int er = (lane >> 4) * 4;
    const int ec = lane & 15;
#pragma unroll
    for (int nj = 0; nj < 4; ++nj)
#pragma unroll
        for (int rr = 0; rr < 4; ++rr)
            atomicAdd(&Sg[(wm2 + er + rr) * 64 + nj * 16 + ec], acc2[nj][rr]);
}

// out_b = q_b @ W2_b^T, fp32 out: grid (32, 8, 2)  (R9's gemm_final verbatim)
__global__ __launch_bounds__(256) void gemm_final(
    const __hip_bfloat16* __restrict__ qb, const __hip_bfloat16* __restrict__ W2,
    float* __restrict__ outg)
{
    __shared__ __align__(16) __hip_bfloat16 As[64 * 64];
    __shared__ __align__(16) __hip_bfloat16 Bs[128 * 64];
    const int b = blockIdx.z;
    gemm_nt_body64_m64(qb + (size_t)b * MM * HH, W2 + (size_t)b * HH * HH,
                       outg + (size_t)b * MM * HH, As, Bs,
                       blockIdx.x * 64, blockIdx.y * 128);
}

// ---------------------------------------------------------------------------
// W2[b][n][h*64+dp] = sum_d Wo[n][h*64+d] * T[b,h,dp,d]   (bf16 out)
// grid (8, KH, BB), block 256  (verified rounds 2-15)
// ---------------------------------------------------------------------------
__global__ __launch_bounds__(256) void w2_fold(
    const __hip_bfloat16* __restrict__ Wo,
    const float* __restrict__ S,
    __hip_bfloat16* __restrict__ W2)
{
    __shared__ float Sl[64 * 68];
    __shared__ float Wl[128 * 68];
    const int t = threadIdx.x, head = blockIdx.y, b = blockIdx.z;
    const int n0 = blockIdx.x * 128;

    const float* Sg = S + ((size_t)b * KH + head) * 4096;
    for (int idx = t; idx < 4096; idx += 256) {
        const int dp = idx >> 6, d = idx & 63;
        Sl[d * 68 + dp] = Sg[idx];
    }
    for (int idx = t; idx < 1024; idx += 256) {
        const int r = idx >> 3, c8 = (idx & 7) * 8;
        s16x8 wv = *(const s16x8*)(Wo + (size_t)(n0 + r) * HH + head * 64 + c8);
#pragma unroll
        for (int j = 0; j < 8; ++j) {
            __hip_bfloat16 wb = *(((const __hip_bfloat16*)&wv) + j);
            Wl[r * 68 + c8 + j] = __bfloat162float(wb);
        }
    }
    __syncthreads();

    const int dpb = (t & 15) * 4;
    const int ng  = t >> 4;
    float acc[8][4] = {};
    for (int d0 = 0; d0 < 64; d0 += 4) {
        f32x4 sv[4];
#pragma unroll
        for (int r = 0; r < 4; ++r)
            sv[r] = *(const f32x4*)(Sl + (d0 + r) * 68 + dpb);
#pragma unroll
        for (int i = 0; i < 8; ++i) {
            const f32x4 wv = *(const f32x4*)(Wl + (ng + 16 * i) * 68 + d0);
#pragma unroll
            for (int r = 0; r < 4; ++r)
#pragma unroll
                for (int j = 0; j < 4; ++j)
                    acc[i][j] += wv[r] * sv[r][j];
        }
    }

#pragma unroll
    for (int i = 0; i < 8; ++i) {
        bf16x4_t o;
        o.x = __float2bfloat16(acc[i][0]);
        o.y = __float2bfloat16(acc[i][1]);
        o.z = __float2bfloat16(acc[i][2]);
        o.w = __float2bfloat16(acc[i][3]);
        *(bf16x4_t*)(W2 + (size_t)b * HH * HH + (size_t)(n0 + ng + 16 * i) * HH
                     + head * 64 + dpb) = o;
    }
}

// ---------------------------------------------------------------------------
extern "C" void kernel_launch(void* const* d_in, const int* in_sizes, int n_in,
                              void* d_out, int out_size, void* d_ws, size_t ws_size,
                              hipStream_t stream) {
    const float* h_f  = (const float*)d_in[0];
    const float* hc_f = (const float*)d_in[1];
    // d_in[2] = key_pe: DEAD (softmax result unused by reference output)
    const float* Wq_f = (const float*)d_in[3];
    const float* Wk_f = (const float*)d_in[4];
    const float* Wv_f = (const float*)d_in[5];
    const float* Wo_f = (const float*)d_in[6];
    float* out = (float*)d_out;

    const size_t act_b = (size_t)BB * MM * HH * 2;  // 8 MB
    const size_t w_b   = (size_t)HH * HH * 2;       // 2 MB
    char* ws = (char*)d_ws;
    __hip_bfloat16* hb   = (__hip_bfloat16*)(ws);                       // 8 MB
    __hip_bfloat16* hcb  = (__hip_bfloat16*)(ws + act_b);               // 8 MB
    __hip_bfloat16* wkb  = (__hip_bfloat16*)(ws + 2 * act_b);           // 2 MB
    __hip_bfloat16* wvb  = (__hip_bfloat16*)(ws + 2 * act_b + w_b);     // 2 MB
    __hip_bfloat16* wob  = (__hip_bfloat16*)(ws + 2 * act_b + 2 * w_b); // 2 MB
    __hip_bfloat16* wqb  = (__hip_bfloat16*)(ws + 2 * act_b + 3 * w_b); // 2 MB
    __hip_bfloat16* qb   = (__hip_bfloat16*)(ws + 2 * act_b + 4 * w_b); // 8 MB
    float*          Sbuf = (float*)(ws + 3 * act_b + 4 * w_b);          // 512 KB
    __hip_bfloat16* W2   = (__hip_bfloat16*)(ws + 3 * act_b + 4 * w_b + (size_t)512 * 1024);  // 4 MB

    const dim3 blk(256);

    // 0: all prep in one dispatch (converts + Sbuf zero)
    cvt_all<<<dim3(4096, 6), blk, 0, stream>>>(h_f, hc_f, Wk_f, Wv_f, Wo_f, Wq_f,
                                               hb, hcb, wkb, wvb, wob, wqb, Sbuf);

    // 1: MEGA: kvt (K/V proj + T, atomics into zeroed Sbuf) + q = h Wq^T
    mega_kvtq<<<dim3(1024), blk, 0, stream>>>(hcb, wkb, wvb, hb, wqb, Sbuf, qb);

    // 2: W2 = blockdiag(T) folded into Wo
    w2_fold<<<dim3(8, KH, BB), blk, 0, stream>>>(wob, Sbuf, W2);

    // 3: out = q @ W2^T (fp32 out)
    gemm_final<<<dim3(32, 8, BB), blk, 0, stream>>>(qb, W2, out);
}

// Round 8
// 158.168 us; speedup vs baseline: 1.1464x; 1.0342x over previous
//
#include <hip/hip_runtime.h>
#include <hip/hip_bf16.h>

// Problem dims (fixed): B=2, M=L=2048, H=1024, K_HEADS=16, D=64
// All inputs/output are FLOAT32; compute in bf16 MFMA with f32 accumulation.
// Algebra: softmax branch is dead; out = Q (K^T V) blockdiag Wo^T, folded as
//   T_h = K_h^T V_h (per head, 64x64)          [fused into the K/V projection]
//   W2[n][h*64+dp] = sum_d Wo[n][h*64+d] T[h][dp][d]   [now MFMA: NT GEMM]
//   q_b  = h_b @ Wq^T                          [re-assoc: out = (h Wq^T) W2^T]
//   out_b = q_b @ W2_b^T
// Round 17 = R16 (measured best, 163.6) with w2_fold replaced by w2_mfma:
// W2-tile = NT(Wo_tile[128x64], S_h[64dp x 64d]) — one K=64 MFMA pass,
// async-staged Wo + reg-staged bf16 S, 1 barrier (was: 1-block/CU VALU kernel
// with 4096 strided scalar S reads). Everything else byte-identical to R16.
#define BB 2
#define MM 2048
#define HH 1024
#define KH 16

typedef short s16x8 __attribute__((ext_vector_type(8)));
typedef float f32x4 __attribute__((ext_vector_type(4)));
typedef float f32x16 __attribute__((ext_vector_type(16)));

#define GLOBAL_AS __attribute__((address_space(1)))
#define LDS_AS    __attribute__((address_space(3)))

__device__ __forceinline__ void async_copy16(const void* g, void* l) {
    __builtin_amdgcn_global_load_lds((const GLOBAL_AS void*)g, (LDS_AS void*)l, 16, 0, 0);
}

struct __align__(8) bf16x4_t { __hip_bfloat16 x, y, z, w; };

// ---------------------------------------------------------------------------
// fused prep: fp32->bf16 converts + Sbuf zero: grid (4096, 6)
// segs 0-4: convert h, h_cache, Wk, Wv, Wo
// seg 5: bx<128 -> zero Sbuf; 128<=bx<1152 -> convert Wq (plain, row-major)
// ---------------------------------------------------------------------------
__global__ __launch_bounds__(256) void cvt_all(
    const float* __restrict__ s0, const float* __restrict__ s1,
    const float* __restrict__ s2, const float* __restrict__ s3,
    const float* __restrict__ s4, const float* __restrict__ Wq,
    __hip_bfloat16* __restrict__ d0, __hip_bfloat16* __restrict__ d1,
    __hip_bfloat16* __restrict__ d2, __hip_bfloat16* __restrict__ d3,
    __hip_bfloat16* __restrict__ d4, __hip_bfloat16* __restrict__ wqb,
    float* __restrict__ Sz)
{
    const int seg = blockIdx.y;
    const int t = threadIdx.x;
    if (seg == 5) {
        const int bx = blockIdx.x;
        if (bx < 128) {                        // zero Sbuf: 131072 floats
            const int i = (bx * 256 + t) * 4;
            float4 z = {0.f, 0.f, 0.f, 0.f};
            *(float4*)(Sz + i) = z;
        } else if (bx < 1152) {                // convert Wq (1024x1024)
            const int i = ((bx - 128) * 256 + t) * 4;
            const float4 v = *(const float4*)(Wq + i);
            bf16x4_t o;
            o.x = __float2bfloat16(v.x);
            o.y = __float2bfloat16(v.y);
            o.z = __float2bfloat16(v.z);
            o.w = __float2bfloat16(v.w);
            *(bf16x4_t*)(wqb + i) = o;
        }
        return;
    }
    const float* src;
    __hip_bfloat16* dst;
    int n;
    switch (seg) {
        case 0: src = s0; dst = d0; n = BB * MM * HH; break;
        case 1: src = s1; dst = d1; n = BB * MM * HH; break;
        case 2: src = s2; dst = d2; n = HH * HH; break;
        case 3: src = s3; dst = d3; n = HH * HH; break;
        default: src = s4; dst = d4; n = HH * HH; break;
    }
    const int i = (blockIdx.x * 256 + t) * 4;
    if (i + 3 < n) {
        const float4 v = *(const float4*)(src + i);
        bf16x4_t o;
        o.x = __float2bfloat16(v.x);
        o.y = __float2bfloat16(v.y);
        o.z = __float2bfloat16(v.z);
        o.w = __float2bfloat16(v.w);
        *(bf16x4_t*)(dst + i) = o;
    }
}

// ---------------------------------------------------------------------------
// store helpers
// ---------------------------------------------------------------------------
__device__ __forceinline__ void store_c(__hip_bfloat16* C, size_t idx, float v) {
    C[idx] = __float2bfloat16(v);
}
__device__ __forceinline__ void store_c(float* C, size_t idx, float v) { C[idx] = v; }

// ---------------------------------------------------------------------------
// 64x128-tile BK=64 NT GEMM body (verified rounds 7-9/16)
// ---------------------------------------------------------------------------
template <typename OutT>
__device__ __forceinline__ void gemm_nt_body64_m64(
    const __hip_bfloat16* __restrict__ A,
    const __hip_bfloat16* __restrict__ Bm,
    OutT* __restrict__ C,
    __hip_bfloat16* As, __hip_bfloat16* Bs,
    int m0, int n0)
{
    const int t    = threadIdx.x;
    const int lane = t & 63;
    const int wave = t >> 6;

    const int srow = lane >> 3;
    const int sw   = ((lane & 7) ^ srow) * 8;

    const int wn  = wave * 32;
    const int fm  = lane & 31;
    const int fm7 = fm & 7;
    const int ghi = lane >> 5;

    f32x16 acc[2] = {};

    for (int k0 = 0; k0 < HH; k0 += 64) {
        __syncthreads();
        {
            const __hip_bfloat16* ag = A + (size_t)(m0 + wave * 16 + srow) * HH + k0 + sw;
            async_copy16(ag,          As + wave * 1024);
            async_copy16(ag + 8 * HH, As + wave * 1024 + 512);
        }
#pragma unroll
        for (int i = 0; i < 2; ++i) {
            const int c = wave * 2 + i;
            const __hip_bfloat16* bg = Bm + (size_t)(n0 + c * 16 + srow) * HH + k0 + sw;
            async_copy16(bg,          Bs + c * 1024);
            async_copy16(bg + 8 * HH, Bs + c * 1024 + 512);
        }
        __syncthreads();

#pragma unroll
        for (int ks = 0; ks < 64; ks += 16) {
            const int pos = ((((ks >> 3) + ghi) ^ fm7) * 8);
            s16x8 af[2], bf;
#pragma unroll
            for (int mi = 0; mi < 2; ++mi)
                af[mi] = *(const s16x8*)(As + (mi * 32 + fm) * 64 + pos);
            bf = *(const s16x8*)(Bs + (wn + fm) * 64 + pos);
#pragma unroll
            for (int mi = 0; mi < 2; ++mi)
                acc[mi] = __builtin_amdgcn_mfma_f32_32x32x16_bf16(
                    af[mi], bf, acc[mi], 0, 0, 0);
        }
    }

    const int ec = lane & 31;
    const int eb = (lane >> 5) * 4;
#pragma unroll
    for (int mi = 0; mi < 2; ++mi)
#pragma unroll
        for (int r = 0; r < 16; ++r) {
            const int m = m0 + mi * 32 + (r & 3) + 8 * (r >> 2) + eb;
            const int n = n0 + wn + ec;
            store_c(C, (size_t)m * HH + n, acc[mi][r]);
        }
}

// ---------------------------------------------------------------------------
// MEGA dispatch: FUSED K/V projection + T = K^T V  (bx < 512, R9-verified)
//                + q = h @ Wq^T tiles              (bx >= 512)
// grid (1024), block 256.  (verbatim from R16, measured 44.7 us / 21% Mfma)
// ---------------------------------------------------------------------------
#define LP2 136

__global__ __launch_bounds__(256) void mega_kvtq(
    const __hip_bfloat16* __restrict__ hcb,
    const __hip_bfloat16* __restrict__ wk, const __hip_bfloat16* __restrict__ wv,
    const __hip_bfloat16* __restrict__ hb, const __hip_bfloat16* __restrict__ wqb,
    float* __restrict__ S, __hip_bfloat16* __restrict__ qb)
{
    __shared__ __align__(16) char smem[64 * LP2 * 2 * 2];  // 34816 B

    const int t    = threadIdx.x;
    const int lane = t & 63;
    const int wave = t >> 6;
    const int bx   = blockIdx.x;

    if (bx >= 512) {                       // ---- q tile: q = h @ Wq^T ----
        __hip_bfloat16* As = (__hip_bfloat16*)smem;            // 8 KB
        __hip_bfloat16* Bs = (__hip_bfloat16*)(smem + 8192);   // 16 KB
        const int idx = bx - 512;          // 0..511: 64 m-tiles x 8 n-tiles
        const int m0 = (idx >> 3) * 64;    // global row in hb [4096][1024]
        const int n0 = (idx & 7) * 128;
        gemm_nt_body64_m64(hb, wqb, qb, As, Bs, m0, n0);
        return;
    }

    // ---- kvt block (R9-verified verbatim; decode from flattened bx) ----
    __hip_bfloat16* As  = (__hip_bfloat16*)smem;            // 16 KB (128x64)
    __hip_bfloat16* Bsk = (__hip_bfloat16*)(smem + 16384);  //  8 KB (64x64)
    __hip_bfloat16* Bsv = (__hip_bfloat16*)(smem + 24576);  //  8 KB (64x64)
    __hip_bfloat16* Kt  = (__hip_bfloat16*)smem;            // 17408 B (64xLP2)
    __hip_bfloat16* Vt  = (__hip_bfloat16*)(smem + 64 * LP2 * 2);

    const int kx   = bx & 31;
    const int head = bx >> 5;
    const int m0   = kx * 128;
    const int n0   = head * 64;
    const int b    = kx >> 4;

    const int srow = lane >> 3;
    const int sw   = ((lane & 7) ^ srow) * 8;

    const int wm  = (wave >> 1) * 64;
    const int wn  = (wave & 1) * 32;
    const int fm  = lane & 31;
    const int fm7 = fm & 7;
    const int ghi = lane >> 5;

    f32x16 acck[2] = {};
    f32x16 accv[2] = {};

    for (int k0 = 0; k0 < HH; k0 += 64) {
        __syncthreads();
#pragma unroll
        for (int i = 0; i < 4; ++i) {
            const int c = wave * 4 + i;
            async_copy16(hcb + (size_t)(m0 + c * 8 + srow) * HH + k0 + sw,
                         As + c * 512);
        }
#pragma unroll
        for (int i = 0; i < 2; ++i) {
            const int c = wave * 2 + i;
            async_copy16(wk + (size_t)(n0 + c * 8 + srow) * HH + k0 + sw,
                         Bsk + c * 512);
            async_copy16(wv + (size_t)(n0 + c * 8 + srow) * HH + k0 + sw,
                         Bsv + c * 512);
        }
        __syncthreads();

#pragma unroll
        for (int ks = 0; ks < 64; ks += 16) {
            const int pos = ((((ks >> 3) + ghi) ^ fm7) * 8);
            s16x8 af[2];
#pragma unroll
            for (int mi = 0; mi < 2; ++mi)
                af[mi] = *(const s16x8*)(As + (wm + mi * 32 + fm) * 64 + pos);
            const s16x8 bk = *(const s16x8*)(Bsk + (wn + fm) * 64 + pos);
            const s16x8 bv = *(const s16x8*)(Bsv + (wn + fm) * 64 + pos);
#pragma unroll
            for (int mi = 0; mi < 2; ++mi) {
                acck[mi] = __builtin_amdgcn_mfma_f32_32x32x16_bf16(af[mi], bk, acck[mi], 0, 0, 0);
                accv[mi] = __builtin_amdgcn_mfma_f32_32x32x16_bf16(af[mi], bv, accv[mi], 0, 0, 0);
            }
        }
    }

    __syncthreads();

    const int dcol = wn + (lane & 31);
    const int lhi  = 4 * (lane >> 5);
#pragma unroll
    for (int mi = 0; mi < 2; ++mi)
#pragma unroll
        for (int g = 0; g < 4; ++g) {
            const int lb = wm + mi * 32 + 8 * g + lhi;
            bf16x4_t ok, ov;
            ok.x = __float2bfloat16(acck[mi][4 * g + 0]);
            ok.y = __float2bfloat16(acck[mi][4 * g + 1]);
            ok.z = __float2bfloat16(acck[mi][4 * g + 2]);
            ok.w = __float2bfloat16(acck[mi][4 * g + 3]);
            ov.x = __float2bfloat16(accv[mi][4 * g + 0]);
            ov.y = __float2bfloat16(accv[mi][4 * g + 1]);
            ov.z = __float2bfloat16(accv[mi][4 * g + 2]);
            ov.w = __float2bfloat16(accv[mi][4 * g + 3]);
            *(bf16x4_t*)(Kt + dcol * LP2 + lb) = ok;
            *(bf16x4_t*)(Vt + dcol * LP2 + lb) = ov;
        }
    __syncthreads();

    const int fr = lane & 15;
    const int fq = (lane >> 4) * 8;
    const int wm2 = wave * 16;

    f32x4 acc2[4] = {};
#pragma unroll
    for (int kk = 0; kk < 128; kk += 32) {
        const s16x8 af = *(const s16x8*)(Kt + (wm2 + fr) * LP2 + kk + fq);
        s16x8 bf[4];
#pragma unroll
        for (int nj = 0; nj < 4; ++nj)
            bf[nj] = *(const s16x8*)(Vt + (nj * 16 + fr) * LP2 + kk + fq);
#pragma unroll
        for (int nj = 0; nj < 4; ++nj)
            acc2[nj] = __builtin_amdgcn_mfma_f32_16x16x32_bf16(af, bf[nj], acc2[nj], 0, 0, 0);
    }

    float* Sg = S + ((size_t)b * KH + head) * 4096;
    const int er = (lane >> 4) * 4;
    const int ec = lane & 15;
#pragma unroll
    for (int nj = 0; nj < 4; ++nj)
#pragma unroll
        for (int rr = 0; rr < 4; ++rr)
            atomicAdd(&Sg[(wm2 + er + rr) * 64 + nj * 16 + ec], acc2[nj][rr]);
}

// out_b = q_b @ W2_b^T, fp32 out: grid (32, 8, 2)  (R9/R16 verbatim)
__global__ __launch_bounds__(256) void gemm_final(
    const __hip_bfloat16* __restrict__ qb, const __hip_bfloat16* __restrict__ W2,
    float* __restrict__ outg)
{
    __shared__ __align__(16) __hip_bfloat16 As[64 * 64];
    __shared__ __align__(16) __hip_bfloat16 Bs[128 * 64];
    const int b = blockIdx.z;
    gemm_nt_body64_m64(qb + (size_t)b * MM * HH, W2 + (size_t)b * HH * HH,
                       outg + (size_t)b * MM * HH, As, Bs,
                       blockIdx.x * 64, blockIdx.y * 128);
}

// ---------------------------------------------------------------------------
// w2_mfma: W2_tile[128n][64dp] = NT(Wo_tile[128n][64d at cols h*64], S_h)
//   S_h is [dp][d] row-major f32 (atomic-accumulated) — exactly the NT
//   B-operand (rows=dp, contraction cols=d). One K=64 pass, 8 MFMA/wave.
// grid (8, KH, BB), block 256. LDS: Ws 16KB (async XOR-swz) + Ss 8KB (reg).
// ---------------------------------------------------------------------------
__global__ __launch_bounds__(256) void w2_mfma(
    const __hip_bfloat16* __restrict__ Wo,
    const float* __restrict__ S,
    __hip_bfloat16* __restrict__ W2)
{
    __shared__ __align__(16) __hip_bfloat16 Ws[128 * 64];  // 16 KB
    __shared__ __align__(16) __hip_bfloat16 Ss[64 * 64];   //  8 KB

    const int t    = threadIdx.x;
    const int lane = t & 63;
    const int wave = t >> 6;
    const int n0   = blockIdx.x * 128;
    const int head = blockIdx.y;
    const int b    = blockIdx.z;

    // stage Wo-tile: rows n0..n0+127, cols head*64..+63 (kvt A-staging pattern)
    {
        const int srow = lane >> 3;
        const int sw   = ((lane & 7) ^ srow) * 8;
#pragma unroll
        for (int i = 0; i < 4; ++i) {
            const int c = wave * 4 + i;                  // 16 groups x 8 rows
            async_copy16(Wo + (size_t)(n0 + c * 8 + srow) * HH + head * 64 + sw,
                         Ws + c * 512);
        }
    }
    // reg-stage S_h (f32 -> bf16) into XOR-swizzled Ss: thread t -> row dp=t>>2
    {
        const float* Sg = S + ((size_t)b * KH + head) * 4096;
        const int dp = t >> 2;
        const int q4 = t & 3;
#pragma unroll
        for (int qq = 0; qq < 4; ++qq) {
            const int d0 = q4 * 16 + qq * 4;
            const f32x4 v = *(const f32x4*)(Sg + dp * 64 + d0);
            bf16x4_t o;
            o.x = __float2bfloat16(v[0]);
            o.y = __float2bfloat16(v[1]);
            o.z = __float2bfloat16(v[2]);
            o.w = __float2bfloat16(v[3]);
            const int slot = (d0 >> 3) ^ (dp & 7);
            *(bf16x4_t*)(Ss + dp * 64 + slot * 8 + (d0 & 7)) = o;
        }
    }
    __syncthreads();

    const int fm  = lane & 31;
    const int fm7 = fm & 7;
    const int ghi = lane >> 5;

    f32x16 acc[2] = {};
#pragma unroll
    for (int ks = 0; ks < 64; ks += 16) {
        const int pos = ((((ks >> 3) + ghi) ^ fm7) * 8);
        const s16x8 af = *(const s16x8*)(Ws + (wave * 32 + fm) * 64 + pos);
#pragma unroll
        for (int nj = 0; nj < 2; ++nj) {
            const s16x8 bf = *(const s16x8*)(Ss + (nj * 32 + fm) * 64 + pos);
            acc[nj] = __builtin_amdgcn_mfma_f32_32x32x16_bf16(af, bf, acc[nj], 0, 0, 0);
        }
    }

    // store: W2[b][n0 + wave*32 + rowpat][head*64 + nj*32 + (lane&31)]
    __hip_bfloat16* W2g = W2 + (size_t)b * HH * HH;
    const int col32 = lane & 31;
    const int rb    = 4 * (lane >> 5);
#pragma unroll
    for (int nj = 0; nj < 2; ++nj)
#pragma unroll
        for (int r = 0; r < 16; ++r) {
            const int row = n0 + wave * 32 + (r & 3) + 8 * (r >> 2) + rb;
            const int col = head * 64 + nj * 32 + col32;
            W2g[(size_t)row * HH + col] = __float2bfloat16(acc[nj][r]);
        }
}

// ---------------------------------------------------------------------------
extern "C" void kernel_launch(void* const* d_in, const int* in_sizes, int n_in,
                              void* d_out, int out_size, void* d_ws, size_t ws_size,
                              hipStream_t stream) {
    const float* h_f  = (const float*)d_in[0];
    const float* hc_f = (const float*)d_in[1];
    // d_in[2] = key_pe: DEAD (softmax result unused by reference output)
    const float* Wq_f = (const float*)d_in[3];
    const float* Wk_f = (const float*)d_in[4];
    const float* Wv_f = (const float*)d_in[5];
    const float* Wo_f = (const float*)d_in[6];
    float* out = (float*)d_out;

    const size_t act_b = (size_t)BB * MM * HH * 2;  // 8 MB
    const size_t w_b   = (size_t)HH * HH * 2;       // 2 MB
    char* ws = (char*)d_ws;
    __hip_bfloat16* hb   = (__hip_bfloat16*)(ws);                       // 8 MB
    __hip_bfloat16* hcb  = (__hip_bfloat16*)(ws + act_b);               // 8 MB
    __hip_bfloat16* wkb  = (__hip_bfloat16*)(ws + 2 * act_b);           // 2 MB
    __hip_bfloat16* wvb  = (__hip_bfloat16*)(ws + 2 * act_b + w_b);     // 2 MB
    __hip_bfloat16* wob  = (__hip_bfloat16*)(ws + 2 * act_b + 2 * w_b); // 2 MB
    __hip_bfloat16* wqb  = (__hip_bfloat16*)(ws + 2 * act_b + 3 * w_b); // 2 MB
    __hip_bfloat16* qb   = (__hip_bfloat16*)(ws + 2 * act_b + 4 * w_b); // 8 MB
    float*          Sbuf = (float*)(ws + 3 * act_b + 4 * w_b);          // 512 KB
    __hip_bfloat16* W2   = (__hip_bfloat16*)(ws + 3 * act_b + 4 * w_b + (size_t)512 * 1024);  // 4 MB

    const dim3 blk(256);

    // 0: all prep in one dispatch (converts + Sbuf zero)
    cvt_all<<<dim3(4096, 6), blk, 0, stream>>>(h_f, hc_f, Wk_f, Wv_f, Wo_f, Wq_f,
                                               hb, hcb, wkb, wvb, wob, wqb, Sbuf);

    // 1: MEGA: kvt (K/V proj + T, atomics into zeroed Sbuf) + q = h Wq^T
    mega_kvtq<<<dim3(1024), blk, 0, stream>>>(hcb, wkb, wvb, hb, wqb, Sbuf, qb);

    // 2: W2 = blockdiag(T) folded into Wo (MFMA, one K=64 pass)
    w2_mfma<<<dim3(8, KH, BB), blk, 0, stream>>>(wob, Sbuf, W2);

    // 3: out = q @ W2^T (fp32 out)
    gemm_final<<<dim3(32, 8, BB), blk, 0, stream>>>(qb, W2, out);
}